// Round 4
// baseline (1786.672 us; speedup 1.0000x reference)
//
#include <hip/hip_runtime.h>

#define B_SZ   65536
#define IN_SZ  256
#define H_SZ   512
#define K_SZ   768          // IN + H
#define BM     32           // rows per block; each block does ALL 1024 output cols
#define BK     64
#define LDK    72           // padded LDS K-stride (bf16 elems); 144 B rows, 16B aligned
#define NCHUNK (K_SZ / BK)  // 12
#define SLDN   516          // epilogue slab stride (floats): 2064 B row stride

typedef __attribute__((ext_vector_type(4))) float          f32x4;
typedef __attribute__((ext_vector_type(8))) __bf16         bf16x8;
typedef __attribute__((ext_vector_type(4))) unsigned short u16x4;

__device__ __forceinline__ unsigned short f2bf(float f) {
    unsigned u = __float_as_uint(f);
    u += 0x7FFFu + ((u >> 16) & 1u);      // round-to-nearest-even
    return (unsigned short)(u >> 16);
}

__device__ __forceinline__ float tanh_fast(float x) {
    x = fminf(fmaxf(x, -16.0f), 16.0f);
    float e = __expf(2.0f * x);
    return (e - 1.0f) / (e + 1.0f);
}

// Build Wt[1024][768] bf16, k-major: rows 0..511 = f-set cols, 512..1023 = c-set cols.
__global__ void prep_weights(const float* __restrict__ w_f, const float* __restrict__ w_c,
                             const float* __restrict__ r_f, const float* __restrict__ r_c,
                             unsigned short* __restrict__ wt) {
    int id = blockIdx.x * 256 + threadIdx.x;
    int n  = id / K_SZ;
    int k  = id - n * K_SZ;
    int col = n & (H_SZ - 1);
    float v;
    if (n < H_SZ) v = (k < IN_SZ) ? w_f[k * H_SZ + col] : r_f[(k - IN_SZ) * H_SZ + col];
    else          v = (k < IN_SZ) ? w_c[k * H_SZ + col] : r_c[(k - IN_SZ) * H_SZ + col];
    wt[(size_t)n * K_SZ + k] = f2bf(v);
}

// Round-4 structure: GATE-SPLIT WAVES to kill K-loop register spills.
// Rounds 1-3 showed WRITE_SIZE = 3.94 GB (7.5x ideal) invariant to the epilogue
// store pattern -> the excess writes are scratch spills from the K-loop, whose
// acc state (128 AGPR) + hoisted global B-frags hit the 256-reg/wave budget
// ((512,2) on the 512-reg/SIMD pool) exactly, with zero arch slack.
// Now: BM=32, 8 waves; wave w computes ONE gate (w&1) over cols
// [(w>>1)*128, +128): acc = 2x8 frags = 64 regs, B-frags live = 16 regs.
// ~150 total regs/wave vs 256 budget -> no spills possible.
// A (x|h rows) still staged once per block (read exactly once from HBM);
// weights read from L2-resident wt (1.5 MB); slab epilogue as round 3.
__launch_bounds__(512, 2)
__global__ void smgu_kernel(const float* __restrict__ x, const float* __restrict__ h_prev,
                            const float* __restrict__ c_prev, const float* __restrict__ n_prev,
                            const float* __restrict__ m_prev,
                            const float* __restrict__ b_f, const float* __restrict__ b_c,
                            const unsigned short* __restrict__ wt,
                            float* __restrict__ out) {
    // union: K-loop uses sA [2][BM][LDK] bf16 = 9216 B;
    //        epilogue uses 2 slabs of [16][SLDN] f32 = 66048 B
    __shared__ __align__(16) unsigned char smem[2 * 16 * SLDN * 4];
    unsigned short* sA    = (unsigned short*)smem;
    float*          slabF = (float*)smem;
    float*          slabC = slabF + 16 * SLDN;

    const int tid  = threadIdx.x;
    const int m0   = blockIdx.x * BM;
    const int lane = tid & 63;
    const int wave = tid >> 6;            // 0..7
    const int gate = wave & 1;            // 0 = F set, 1 = C set
    const int cg   = wave >> 1;           // col group: 128 cols each
    const int nb   = gate * H_SZ + cg * 128;   // wt row base for this wave
    const int fr   = lane & 15;
    const int fg   = (lane >> 4) * 8;     // k-octet offset
    const int g    = lane >> 4;

    f32x4 acc[2][8];
#pragma unroll
    for (int i = 0; i < 2; ++i)
#pragma unroll
        for (int j = 0; j < 8; ++j) acc[i][j] = (f32x4)0.0f;

    // staging map: 512 float4 chunks (32 rows x 16), exactly one per thread
    const int r0s = tid >> 4;             // 0..31
    const int c4s = tid & 15;

    f32x4 pv;
    auto load_chunk = [&](int kb) {
        const float* src; int ld, kl;
        if (kb < IN_SZ) { src = x;      ld = IN_SZ; kl = kb; }
        else            { src = h_prev; ld = H_SZ;  kl = kb - IN_SZ; }
        pv = __builtin_nontemporal_load(
            (const f32x4*)&src[(size_t)(m0 + r0s) * ld + kl + c4s * 4]);
    };
    auto write_chunk = [&](int buf) {
        u16x4 w0;
        w0[0] = f2bf(pv[0]); w0[1] = f2bf(pv[1]); w0[2] = f2bf(pv[2]); w0[3] = f2bf(pv[3]);
        *(u16x4*)&sA[(buf * BM + r0s) * LDK + c4s * 4] = w0;
    };

    load_chunk(0);
    write_chunk(0);
    __syncthreads();

    for (int t = 0; t < NCHUNK; ++t) {
        const int cur = t & 1;
        if (t + 1 < NCHUNK) load_chunk((t + 1) * BK);   // HBM latency hides under MFMAs
        const unsigned short* sAc = &sA[cur * BM * LDK];
#pragma unroll
        for (int ks = 0; ks < BK; ks += 32) {
            bf16x8 af[2];
#pragma unroll
            for (int mi = 0; mi < 2; ++mi)
                af[mi] = *(const bf16x8*)&sAc[(mi * 16 + fr) * LDK + ks + fg];
            const int kk = t * BK + ks + fg;
            // two ni-halves: at most 4 B-frags (16 regs) live at a time
#pragma unroll
            for (int nh = 0; nh < 2; ++nh) {
                bf16x8 b[4];
#pragma unroll
                for (int ni = 0; ni < 4; ++ni)
                    b[ni] = *(const bf16x8*)&wt[(size_t)(nb + nh * 64 + ni * 16 + fr) * K_SZ + kk];  // L2 hit
#pragma unroll
                for (int mi = 0; mi < 2; ++mi)
#pragma unroll
                    for (int ni = 0; ni < 4; ++ni)
                        acc[mi][nh * 4 + ni] =
                            __builtin_amdgcn_mfma_f32_16x16x32_bf16(af[mi], b[ni], acc[mi][nh * 4 + ni], 0, 0, 0);
            }
        }
        if (t + 1 < NCHUNK) write_chunk(cur ^ 1);
        __syncthreads();   // final iter: fences LDS before epilogue slab reuse
    }

    // ---- epilogue: block-linear via LDS slab exchange (2 rounds of 16 rows).
    // MFMA C/D layout: col = ni*16 + (lane&15), row = (lane>>4)*4 + reg  [m89/m91]
    const size_t BH = (size_t)B_SZ * H_SZ;
    float* slab = gate ? slabC : slabF;

#pragma unroll 1
    for (int mi = 0; mi < 2; ++mi) {
        // stage raw pre-activations for these 16 rows; F-waves -> slabF, C-waves -> slabC
#pragma unroll
        for (int ni = 0; ni < 8; ++ni)
#pragma unroll
            for (int r = 0; r < 4; ++r) {
                const int rl = g * 4 + r;
                const int cc = cg * 128 + ni * 16 + fr;
                slab[rl * SLDN + cc] = acc[mi][ni][r];
            }
        __syncthreads();

        // linear pass: 16 rows x 512 cols = 2048 f32x4 chunks; 4 per thread
#pragma unroll
        for (int j = 0; j < 4; ++j) {
            const int flat = tid + 512 * j;
            const int row  = flat >> 7;          // 0..15
            const int c4   = flat & 127;         // f32x4 column index
            const size_t idx = (size_t)(m0 + mi * 16 + row) * H_SZ + c4 * 4;
            f32x4 pF = *(const f32x4*)&slabF[row * SLDN + c4 * 4];
            f32x4 pC = *(const f32x4*)&slabC[row * SLDN + c4 * 4];
            f32x4 bfv = *(const f32x4*)&b_f[c4 * 4];
            f32x4 bcv = *(const f32x4*)&b_c[c4 * 4];
            f32x4 cp = __builtin_nontemporal_load((const f32x4*)&c_prev[idx]);
            f32x4 np = __builtin_nontemporal_load((const f32x4*)&n_prev[idx]);
            f32x4 mp = __builtin_nontemporal_load((const f32x4*)&m_prev[idx]);
            f32x4 ho, co, no, mo;
#pragma unroll
            for (int q = 0; q < 4; ++q) {
                float preF = pF[q] + bfv[q];
                float s    = preF + mp[q];
                float mt   = fmaxf(s, 0.0f);
                float ipv  = __expf(-mt);
                float fpv  = __expf(s - mt);
                float ct   = fpv * cp[q] + ipv * tanh_fast(pC[q] + bcv[q]);
                float ntv  = fpv * np[q] + ipv;
                float htv  = tanh_fast(ct / fmaxf(ntv, 1e-8f));
                ho[q] = htv; co[q] = ct; no[q] = ntv; mo[q] = mt;
            }
            *(f32x4*)&out[idx]          = ho;
            *(f32x4*)&out[BH + idx]     = co;
            *(f32x4*)&out[2 * BH + idx] = no;
            *(f32x4*)&out[3 * BH + idx] = mo;
        }
        __syncthreads();   // slabs reused next mi
    }
}

extern "C" void kernel_launch(void* const* d_in, const int* in_sizes, int n_in,
                              void* d_out, int out_size, void* d_ws, size_t ws_size,
                              hipStream_t stream) {
    const float* x      = (const float*)d_in[0];
    const float* h_prev = (const float*)d_in[1];
    const float* c_prev = (const float*)d_in[2];
    const float* n_prev = (const float*)d_in[3];
    const float* m_prev = (const float*)d_in[4];
    const float* w_f    = (const float*)d_in[5];
    const float* w_c    = (const float*)d_in[6];
    const float* r_f    = (const float*)d_in[7];
    const float* r_c    = (const float*)d_in[8];
    const float* b_f    = (const float*)d_in[9];
    const float* b_c    = (const float*)d_in[10];
    float* out = (float*)d_out;
    unsigned short* wt = (unsigned short*)d_ws;   // 1024*768*2 = 1.5 MiB

    prep_weights<<<(2 * H_SZ * K_SZ) / 256, 256, 0, stream>>>(w_f, w_c, r_f, r_c, wt);
    smgu_kernel<<<B_SZ / BM, 512, 0, stream>>>(
        x, h_prev, c_prev, n_prev, m_prev, b_f, b_c, wt, out);
}

// Round 5
// 1613.626 us; speedup vs baseline: 1.1072x; 1.1072x over previous
//
#include <hip/hip_runtime.h>

#define B_SZ   65536
#define IN_SZ  256
#define H_SZ   512
#define K_SZ   768          // IN + H
#define BM     64           // rows per block; each block does ALL 1024 output cols
#define BK     64
#define LDK    72           // padded LDS K-stride (bf16 elems); 144 B rows, 16B aligned
#define NCHUNK (K_SZ / BK)  // 12
#define SLDN   516          // epilogue slab stride (floats): 2064 B row stride

typedef __attribute__((ext_vector_type(4))) float          f32x4;
typedef __attribute__((ext_vector_type(8))) __bf16         bf16x8;
typedef __attribute__((ext_vector_type(4))) unsigned short u16x4;

__device__ __forceinline__ unsigned short f2bf(float f) {
    unsigned u = __float_as_uint(f);
    u += 0x7FFFu + ((u >> 16) & 1u);      // round-to-nearest-even
    return (unsigned short)(u >> 16);
}

__device__ __forceinline__ float tanh_fast(float x) {
    x = fminf(fmaxf(x, -16.0f), 16.0f);
    float e = __expf(2.0f * x);
    return (e - 1.0f) / (e + 1.0f);
}

// Build Wt[1024][768] bf16, k-major: rows 0..511 = f-set cols, 512..1023 = c-set cols.
__global__ void prep_weights(const float* __restrict__ w_f, const float* __restrict__ w_c,
                             const float* __restrict__ r_f, const float* __restrict__ r_c,
                             unsigned short* __restrict__ wt) {
    int id = blockIdx.x * 256 + threadIdx.x;
    int n  = id / K_SZ;
    int k  = id - n * K_SZ;
    int col = n & (H_SZ - 1);
    float v;
    if (n < H_SZ) v = (k < IN_SZ) ? w_f[k * H_SZ + col] : r_f[(k - IN_SZ) * H_SZ + col];
    else          v = (k < IN_SZ) ? w_c[k * H_SZ + col] : r_c[(k - IN_SZ) * H_SZ + col];
    wt[(size_t)n * K_SZ + k] = f2bf(v);
}

// Round-5: round-3 structure (the fastest: 938 us) with ALL nontemporal load
// qualifiers removed — single-variable A/B. Rounds 1-4 established the ~3.45 GB
// of excess HBM writes are invariant to store policy, store pattern, epilogue
// structure, VGPR pressure, and block count; the only memory-path variable
// common to rounds 1-4 and absent in round 0 (0.84 GB writes) is nt loads on
// the streaming reads. If WRITE_SIZE collapses, nt loads were morphing read
// traffic into MALL write churn; if unchanged, next suspect is the K-loop's
// direct-from-global wt reads (round 0 staged wt via LDS).
__launch_bounds__(512, 2)
__global__ void smgu_kernel(const float* __restrict__ x, const float* __restrict__ h_prev,
                            const float* __restrict__ c_prev, const float* __restrict__ n_prev,
                            const float* __restrict__ m_prev,
                            const float* __restrict__ b_f, const float* __restrict__ b_c,
                            const unsigned short* __restrict__ wt,
                            float* __restrict__ out) {
    // union: K-loop uses sA [2][BM][LDK] bf16 = 18432 B;
    //        epilogue uses 2 slabs of [16][SLDN] f32 = 66048 B
    __shared__ __align__(16) unsigned char smem[2 * 16 * SLDN * 4];
    unsigned short* sA    = (unsigned short*)smem;
    float*          slabF = (float*)smem;
    float*          slabC = slabF + 16 * SLDN;

    const int tid  = threadIdx.x;
    const int m0   = blockIdx.x * BM;
    const int lane = tid & 63;
    const int wave = tid >> 6;            // 0..7 -> H-col group
    const int n0   = wave * 64;
    const int fr   = lane & 15;
    const int fg   = (lane >> 4) * 8;     // k-octet offset
    const int g    = lane >> 4;

    f32x4 accF[4][4], accC[4][4];
#pragma unroll
    for (int i = 0; i < 4; ++i)
#pragma unroll
        for (int j = 0; j < 4; ++j) { accF[i][j] = (f32x4)0.0f; accC[i][j] = (f32x4)0.0f; }

    // staging map: 1024 float4 chunks (64 rows x 16), thread does chunks tid and tid+512
    const int r0s = tid >> 4;             // 0..31
    const int c4s = tid & 15;

    f32x4 pv0, pv1;
    auto load_chunk = [&](int kb) {
        const float* src; int ld, kl;
        if (kb < IN_SZ) { src = x;      ld = IN_SZ; kl = kb; }
        else            { src = h_prev; ld = H_SZ;  kl = kb - IN_SZ; }
        pv0 = *(const f32x4*)&src[(size_t)(m0 + r0s) * ld + kl + c4s * 4];
        pv1 = *(const f32x4*)&src[(size_t)(m0 + 32 + r0s) * ld + kl + c4s * 4];
    };
    auto write_chunk = [&](int buf) {
        u16x4 w0, w1;
        w0[0] = f2bf(pv0[0]); w0[1] = f2bf(pv0[1]); w0[2] = f2bf(pv0[2]); w0[3] = f2bf(pv0[3]);
        w1[0] = f2bf(pv1[0]); w1[1] = f2bf(pv1[1]); w1[2] = f2bf(pv1[2]); w1[3] = f2bf(pv1[3]);
        *(u16x4*)&sA[(buf * BM + r0s) * LDK + c4s * 4]      = w0;
        *(u16x4*)&sA[(buf * BM + 32 + r0s) * LDK + c4s * 4] = w1;
    };

    load_chunk(0);
    write_chunk(0);
    __syncthreads();

    for (int t = 0; t < NCHUNK; ++t) {
        const int cur = t & 1;
        if (t + 1 < NCHUNK) load_chunk((t + 1) * BK);   // HBM latency hides under MFMAs
        const unsigned short* sAc = &sA[cur * BM * LDK];
#pragma unroll
        for (int ks = 0; ks < BK; ks += 32) {
            bf16x8 af[4], bfx[4], bcx[4];
#pragma unroll
            for (int mi = 0; mi < 4; ++mi)
                af[mi] = *(const bf16x8*)&sAc[(mi * 16 + fr) * LDK + ks + fg];
            const int kk = t * BK + ks + fg;
#pragma unroll
            for (int ni = 0; ni < 4; ++ni) {
                const int nr = n0 + ni * 16 + fr;
                bfx[ni] = *(const bf16x8*)&wt[(size_t)nr * K_SZ + kk];            // L2 hit
                bcx[ni] = *(const bf16x8*)&wt[(size_t)(H_SZ + nr) * K_SZ + kk];   // L2 hit
            }
#pragma unroll
            for (int mi = 0; mi < 4; ++mi)
#pragma unroll
                for (int ni = 0; ni < 4; ++ni) {
                    accF[mi][ni] = __builtin_amdgcn_mfma_f32_16x16x32_bf16(af[mi], bfx[ni], accF[mi][ni], 0, 0, 0);
                    accC[mi][ni] = __builtin_amdgcn_mfma_f32_16x16x32_bf16(af[mi], bcx[ni], accC[mi][ni], 0, 0, 0);
                }
        }
        if (t + 1 < NCHUNK) write_chunk(cur ^ 1);
        __syncthreads();   // final iter: fences LDS before epilogue slab reuse
    }

    // ---- epilogue: block-linear via LDS slab exchange.
    // MFMA C/D layout: col = ni*16 + (lane&15), row = (lane>>4)*4 + reg  [m89/m91]
    const size_t BH = (size_t)B_SZ * H_SZ;

#pragma unroll 1
    for (int mi = 0; mi < 4; ++mi) {
        // stage raw pre-activations for these 16 rows x 512 cols
#pragma unroll
        for (int ni = 0; ni < 4; ++ni)
#pragma unroll
            for (int r = 0; r < 4; ++r) {
                const int rl = g * 4 + r;
                const int cc = n0 + ni * 16 + fr;
                slabF[rl * SLDN + cc] = accF[mi][ni][r];
                slabC[rl * SLDN + cc] = accC[mi][ni][r];
            }
        __syncthreads();

        // linear pass: 16 rows x 512 cols = 2048 f32x4 chunks; 4 per thread
#pragma unroll
        for (int j = 0; j < 4; ++j) {
            const int flat = tid + 512 * j;
            const int row  = flat >> 7;          // 0..15
            const int c4   = flat & 127;         // f32x4 column index
            const size_t idx = (size_t)(m0 + mi * 16 + row) * H_SZ + c4 * 4;
            f32x4 pF = *(const f32x4*)&slabF[row * SLDN + c4 * 4];
            f32x4 pC = *(const f32x4*)&slabC[row * SLDN + c4 * 4];
            f32x4 bfv = *(const f32x4*)&b_f[c4 * 4];
            f32x4 bcv = *(const f32x4*)&b_c[c4 * 4];
            f32x4 cp = *(const f32x4*)&c_prev[idx];
            f32x4 np = *(const f32x4*)&n_prev[idx];
            f32x4 mp = *(const f32x4*)&m_prev[idx];
            f32x4 ho, co, no, mo;
#pragma unroll
            for (int q = 0; q < 4; ++q) {
                float preF = pF[q] + bfv[q];
                float s    = preF + mp[q];
                float mt   = fmaxf(s, 0.0f);
                float ipv  = __expf(-mt);
                float fpv  = __expf(s - mt);
                float ct   = fpv * cp[q] + ipv * tanh_fast(pC[q] + bcv[q]);
                float ntv  = fpv * np[q] + ipv;
                float htv  = tanh_fast(ct / fmaxf(ntv, 1e-8f));
                ho[q] = htv; co[q] = ct; no[q] = ntv; mo[q] = mt;
            }
            *(f32x4*)&out[idx]          = ho;
            *(f32x4*)&out[BH + idx]     = co;
            *(f32x4*)&out[2 * BH + idx] = no;
            *(f32x4*)&out[3 * BH + idx] = mo;
        }
        __syncthreads();   // slabs reused next mi
    }
}

extern "C" void kernel_launch(void* const* d_in, const int* in_sizes, int n_in,
                              void* d_out, int out_size, void* d_ws, size_t ws_size,
                              hipStream_t stream) {
    const float* x      = (const float*)d_in[0];
    const float* h_prev = (const float*)d_in[1];
    const float* c_prev = (const float*)d_in[2];
    const float* n_prev = (const float*)d_in[3];
    const float* m_prev = (const float*)d_in[4];
    const float* w_f    = (const float*)d_in[5];
    const float* w_c    = (const float*)d_in[6];
    const float* r_f    = (const float*)d_in[7];
    const float* r_c    = (const float*)d_in[8];
    const float* b_f    = (const float*)d_in[9];
    const float* b_c    = (const float*)d_in[10];
    float* out = (float*)d_out;
    unsigned short* wt = (unsigned short*)d_ws;   // 1024*768*2 = 1.5 MiB

    prep_weights<<<(2 * H_SZ * K_SZ) / 256, 256, 0, stream>>>(w_f, w_c, r_f, r_c, wt);
    smgu_kernel<<<B_SZ / BM, 512, 0, stream>>>(
        x, h_prev, c_prev, n_prev, m_prev, b_f, b_c, wt, out);
}